// Round 6
// baseline (71.221 us; speedup 1.0000x reference)
//
#include <hip/hip_runtime.h>
#include <math.h>

#define BB 16384
#define NSTEPS 32
#define HH 128
#define DTF (1.0f/32.0f)
#define SCALE 2.88539008177792681f   // 2*log2(e):  e^{2x} = 2^{SCALE*x}
#define LOG2E 1.44269504088896340f

typedef float v2f __attribute__((ext_vector_type(2)));
typedef float v8f __attribute__((ext_vector_type(8)));
typedef unsigned int v2u __attribute__((ext_vector_type(2)));

__device__ __forceinline__ v2f pk_fma(v2f a, v2f b, v2f c) {
    return __builtin_elementwise_fma(a, b, c);   // -> v_pk_fma_f32
}

// packed fast reciprocal: bit-trick estimate + 1 Newton. Valid x in [1, ~1e38].
// max rel err ~0.1% after Newton — inside this problem's error budget (R5: 0.031 abs).
__device__ __forceinline__ v2f pk_rcp1(v2f x) {
    v2u xb; __builtin_memcpy(&xb, &x, 8);
    v2u yb = (v2u){0x7EF311C3u, 0x7EF311C3u} - xb;
    v2f y;  __builtin_memcpy(&y, &yb, 8);
    v2f u = pk_fma(-x, y, (v2f){2.0f, 2.0f});    // 2 - x*y
    return y * u;
}

__device__ __forceinline__ float fexp2(float x) {
#if __has_builtin(__builtin_amdgcn_exp2f)
    return __builtin_amdgcn_exp2f(x);
#else
    float r; asm("v_exp_f32 %0, %1" : "=v"(r) : "v"(x)); return r;
#endif
}
__device__ __forceinline__ float frcp(float x) {
#if __has_builtin(__builtin_amdgcn_rcpf)
    return __builtin_amdgcn_rcpf(x);
#else
    float r; asm("v_rcp_f32 %0, %1" : "=v"(r) : "v"(x)); return r;
#endif
}
__device__ __forceinline__ float frsq(float x) {
#if __has_builtin(__builtin_amdgcn_rsqf)
    return __builtin_amdgcn_rsqf(x);
#else
    float r; asm("v_rsq_f32 %0, %1" : "=v"(r) : "v"(x)); return r;
#endif
}

// ---------------------------------------------------------------------------
// Transform kernel. Record per (i,j), 16 floats, (g,j) interleaved:
//  [0,1]=(S*gw0,S*jw0) [2,3]=(S*gw1,S*jw1) [4,5]=(S*gw2,S*jw2)
//  [6,7]=(S*gw3,S*jw3) [8,9]=(S*gb1,S*jb1) [10,11]=(-2g20,-2g21)
//  [12,13]=(-2g22,-2jW2) [14,15]=(e^{2jw0}, e^{-2jw0})
// ---------------------------------------------------------------------------
__global__ __launch_bounds__(HH) void xform_kernel(
    const float* __restrict__ gW1, const float* __restrict__ gb1,
    const float* __restrict__ gW2, const float* __restrict__ gb2,
    const float* __restrict__ jW1, const float* __restrict__ jb1,
    const float* __restrict__ jW2,
    float* __restrict__ recA, float* __restrict__ G)
{
    const int i = blockIdx.x;    // step
    const int j = threadIdx.x;   // hidden unit
    float* r = recA + ((size_t)(i*HH + j)) * 16;

    const float* gw = gW1 + (size_t)(i*HH + j)*4;
    const float* jw = jW1 + (size_t)(i*HH + j)*4;
    float jw0 = jw[0];
    r[0] = SCALE*gw[0]; r[1] = SCALE*jw0;
    r[2] = SCALE*gw[1]; r[3] = SCALE*jw[1];
    r[4] = SCALE*gw[2]; r[5] = SCALE*jw[2];
    r[6] = SCALE*gw[3]; r[7] = SCALE*jw[3];
    r[8] = SCALE*gb1[i*HH + j];
    r[9] = SCALE*jb1[i*HH + j];
    float g20 = gW2[i*3*HH + 0*HH + j];
    float g21 = gW2[i*3*HH + 1*HH + j];
    float g22 = gW2[i*3*HH + 2*HH + j];
    r[10] = -2.0f*g20; r[11] = -2.0f*g21;
    r[12] = -2.0f*g22; r[13] = -2.0f*jW2[i*HH + j];
    r[14] = exp2f( SCALE*jw0);
    r[15] = exp2f(-SCALE*jw0);

    __shared__ float sh[3*HH];
    sh[0*HH + j] = g20; sh[1*HH + j] = g21; sh[2*HH + j] = g22;
    __syncthreads();
    if (j < 3) {
        float s = gb2[i*3 + j];
        for (int t = 0; t < HH; ++t) s += sh[j*HH + t];
        G[i*4 + j] = s;
    }
}

// ---------------------------------------------------------------------------
// Main kernel. Block = 256 threads = 128 batch-slots x 2 j-halves; each
// thread processes TWO batch elements (b and b+128) so every 64 B weight
// record (scalar s_load, shared via readfirstlane'd jh) serves 2x the work
// and the two independent sigmoid chains fill dependency bubbles.
// Grid = 32 steps x 64 = 2048 blocks = exactly full residency (32 waves/CU).
// ---------------------------------------------------------------------------
__global__ __launch_bounds__(256, 8) void step_kernel(
    const float* __restrict__ N, const float* __restrict__ X,
    const float* __restrict__ T, const float* __restrict__ dB,
    const float* __restrict__ recA, const float* __restrict__ G,
    float* __restrict__ C)
{
    const int tid  = threadIdx.x;
    const int i    = blockIdx.x >> 6;          // step (block-uniform)
    const int bblk = blockIdx.x & 63;
    const int bl   = tid & 127;                // local batch slot
    const int jh   = __builtin_amdgcn_readfirstlane(tid >> 7);  // wave-uniform -> SGPR
    const int b0   = bblk*256 + bl;            // second element is b0+128
    const int ib0  = i*BB + b0;

    float Ni[2], xx0[2], xx1[2], xx2[2];
#pragma unroll
    for (int p = 0; p < 2; ++p) {
        const int ib = ib0 + p*128;
        Ni[p]  = N[ib];
        xx0[p] = X[(size_t)ib*3 + 0];
        xx1[p] = X[(size_t)ib*3 + 1];
        xx2[p] = X[(size_t)ib*3 + 2];
    }

    const v8f* rec8 = (const v8f*)(recA + (size_t)i*HH*16) + (size_t)jh*128;

    const v2f one = {1.0f, 1.0f};
    const v2f c25 = {25.0f, 25.0f};

    v2f ga01[2] = {{0.f,0.f},{0.f,0.f}};   // (sum -2g20*rg, sum -2g21*rg)
    v2f g2a0[2] = {{0.f,0.f},{0.f,0.f}};   // (sum -2g22*rg, sum -2jW2*r0)
    v2f aPM [2] = {{0.f,0.f},{0.f,0.f}};   // (sum -2jW2*rp, sum -2jW2*rm)

#pragma unroll 2
    for (int t = 0; t < 64; ++t) {
        const v8f A  = rec8[2*t + 0];    // W1 rows, interleaved (g,j)
        const v8f Bv = rec8[2*t + 1];    // [gb,jb, -2g20,-2g21, -2g22,-2jW2, cp,cm]

#pragma unroll
        for (int p = 0; p < 2; ++p) {
            v2f acc = {Bv[0], Bv[1]};
            acc = pk_fma((v2f){A[0], A[1]}, (v2f){Ni[p],  Ni[p]},  acc);
            acc = pk_fma((v2f){A[2], A[3]}, (v2f){xx0[p], xx0[p]}, acc);
            acc = pk_fma((v2f){A[4], A[5]}, (v2f){xx1[p], xx1[p]}, acc);
            acc = pk_fma((v2f){A[6], A[7]}, (v2f){xx2[p], xx2[p]}, acc);
            acc = __builtin_elementwise_min(acc, c25);   // keep exp2 finite (rcp1 domain)

            const float eg = fexp2(acc[0]);
            const float eb = fexp2(acc[1]);

            v2f t01 = (v2f){eg, eb} + one;                              // (tg, t0)
            v2f tpm = pk_fma((v2f){eb, eb}, (v2f){Bv[6], Bv[7]}, one);  // (tp, tm)

            v2f r01 = pk_rcp1(t01);   // (1/tg, 1/t0)
            v2f rpm = pk_rcp1(tpm);   // (1/tp, 1/tm)

            ga01[p] = pk_fma((v2f){Bv[2], Bv[3]}, (v2f){r01[0], r01[0]}, ga01[p]);
            g2a0[p] = pk_fma((v2f){Bv[4], Bv[5]}, r01, g2a0[p]);
            aPM [p] = pk_fma((v2f){Bv[5], Bv[5]}, rpm, aPM[p]);
        }
    }

    __shared__ float sh[6][256];
    if (jh) {
#pragma unroll
        for (int p = 0; p < 2; ++p) {
            const int s = bl + p*128;
            sh[0][s] = ga01[p][0]; sh[1][s] = ga01[p][1]; sh[2][s] = g2a0[p][0];
            sh[3][s] = g2a0[p][1]; sh[4][s] = aPM[p][0];  sh[5][s] = aPM[p][1];
        }
    }
    __syncthreads();
    if (!jh) {
        const float G0 = G[i*4 + 0], G1 = G[i*4 + 1], G2 = G[i*4 + 2];
        const float ti = T[i];
#pragma unroll
        for (int p = 0; p < 2; ++p) {
            const int s  = bl + p*128;
            const int ib = ib0 + p*128;

            const float g0 = G0 + ga01[p][0] + sh[0][s];
            const float g1 = G1 + ga01[p][1] + sh[1][s];
            const float g2 = G2 + g2a0[p][0] + sh[2][s];
            const float a0 = g2a0[p][1] + sh[3][s];
            const float aP = aPM[p][0]  + sh[4][s];
            const float aM = aPM[p][1]  + sh[5][s];

            const float nn  = Ni[p];
            const float y0 = xx0[p], y1 = xx1[p], y2 = xx2[p];
            const float Np1 = N[ib + BB];
            const float d0 = dB[(size_t)ib*3 + 0], d1 = dB[(size_t)ib*3 + 1], d2 = dB[(size_t)ib*3 + 2];

            const float gdx = g0*y0 + g1*y1 + g2*y2;          // grad_u . x
            const float ss  = y0*y0 + y1*y1 + y2*y2;          // x . x
            const float gdB = g0*d0 + g1*d1 + g2*d2;          // grad_u . dB
            const float xdB = y0*d0 + y1*d1 + y2*d2;          // x . dB

            const float k = 1.41421356237309505f * frsq(fmaf(0.1f*nn, nn, 1.0f));
            // kg^T (I+o)(I-o) dB = k*(g.dB - (x.x)*(g.x)*(x.dB))
            const float grad_bmm = k * (gdB - ss*gdx*xdB);

            const float dp = aP - a0;
            const float dm = aM - a0;

            // alpha = 0.3*sig(0.1 N), beta = 0.2*(1-sig(0.1 N))
            const float sig = frcp(1.0f + fexp2(-0.1f*LOG2E*nn));
            const float alpha = 0.3f*sig;
            const float beta  = 0.2f - 0.2f*sig;

            const float dd = Np1 - nn;                        // exact -1/0/+1
            const float jump = (dd > 0.5f) ? dp : ((dd < -0.5f) ? dm : 0.0f);

            const float c = grad_bmm - (alpha*dp + beta*dm)*DTF
                          - 0.05f*DTF*gdx - 0.01f*DTF*ti + jump;
            C[ib] = c;
        }
    }
}

// ---------------------------------------------------------------------------
// Final kernel: u0 via r-MLP parallelized 16 lanes per batch element
// (shuffle-reduce), then 32-step affine scan on the group leader.
// ---------------------------------------------------------------------------
__global__ __launch_bounds__(256) void final_kernel(
    const float* __restrict__ N, const float* __restrict__ X,
    const float* __restrict__ rW1, const float* __restrict__ rb1,
    const float* __restrict__ rW2, const float* __restrict__ rb2,
    const float* __restrict__ C, float* __restrict__ out)
{
    const int gid = blockIdx.x*256 + threadIdx.x;
    const int b = gid >> 4;          // batch element
    const int p = gid & 15;          // 16-way split over hidden units

    const float n0 = N[b];
    const float x0 = X[(size_t)b*3 + 0], x1 = X[(size_t)b*3 + 1], x2 = X[(size_t)b*3 + 2];

    float accw = 0.f, accr = 0.f;
#pragma unroll
    for (int t = 0; t < 8; ++t) {
        const int j = p*8 + t;
        float pre = fmaf(rW1[j*4+0], n0, fmaf(rW1[j*4+1], x0,
                    fmaf(rW1[j*4+2], x1, fmaf(rW1[j*4+3], x2, rb1[j]))));
        float r  = frcp(1.0f + fexp2(SCALE*pre));
        float w2 = rW2[j];
        accw += w2;
        accr = fmaf(w2, r, accr);
    }
    accw += __shfl_down(accw, 8, 16);  accr += __shfl_down(accr, 8, 16);
    accw += __shfl_down(accw, 4, 16);  accr += __shfl_down(accr, 4, 16);
    accw += __shfl_down(accw, 2, 16);  accr += __shfl_down(accr, 2, 16);
    accw += __shfl_down(accw, 1, 16);  accr += __shfl_down(accr, 1, 16);

    if (p == 0) {
        float u = rb2[0] + accw - 2.0f*accr;    // rb2 + sum w2*tanh

        const float sfac = 1.0f + 0.05f*DTF;
#pragma unroll
        for (int i = 0; i < NSTEPS; ++i)
            u = fmaf(u, sfac, C[(size_t)i*BB + b]);
        out[b] = u;

        const int ib = NSTEPS*BB + b;
        out[BB + b] = fmaf(0.1f, N[ib], __cosf(X[(size_t)ib*3]));
    }
}

// ---------------------------------------------------------------------------
extern "C" void kernel_launch(void* const* d_in, const int* in_sizes, int n_in,
                              void* d_out, int out_size, void* d_ws, size_t ws_size,
                              hipStream_t stream)
{
    const float* N   = (const float*)d_in[0];
    const float* X   = (const float*)d_in[1];
    const float* T   = (const float*)d_in[2];
    const float* dB  = (const float*)d_in[3];
    const float* rW1 = (const float*)d_in[4];
    const float* rb1 = (const float*)d_in[5];
    const float* rW2 = (const float*)d_in[6];
    const float* rb2 = (const float*)d_in[7];
    const float* gW1 = (const float*)d_in[8];
    const float* gb1 = (const float*)d_in[9];
    const float* gW2 = (const float*)d_in[10];
    const float* gb2 = (const float*)d_in[11];
    const float* jW1 = (const float*)d_in[12];
    const float* jb1 = (const float*)d_in[13];
    const float* jW2 = (const float*)d_in[14];
    // jb2 (d_in[15]) cancels in dp/dm — unused.

    float* ws   = (float*)d_ws;
    float* C    = ws;                                  // 32*16384 floats
    float* recA = ws + (size_t)NSTEPS*BB;              // 32*128*16 floats
    float* G    = recA + (size_t)NSTEPS*HH*16;         // 128 floats
    float* out  = (float*)d_out;

    xform_kernel<<<NSTEPS, HH, 0, stream>>>(gW1, gb1, gW2, gb2, jW1, jb1, jW2, recA, G);
    step_kernel<<<NSTEPS*(BB/256), 256, 0, stream>>>(N, X, T, dB, recA, G, C);
    final_kernel<<<BB*16/256, 256, 0, stream>>>(N, X, rW1, rb1, rW2, rb2, C, out);
}

// Round 7
// 64.975 us; speedup vs baseline: 1.0961x; 1.0961x over previous
//
#include <hip/hip_runtime.h>
#include <math.h>

#define BB 16384
#define NSTEPS 32
#define HH 128
#define DTF (1.0f/32.0f)
#define SCALE 2.88539008177792681f   // 2*log2(e):  e^{2x} = 2^{SCALE*x}
#define LOG2E 1.44269504088896340f

typedef float v2f __attribute__((ext_vector_type(2)));
typedef float v8f __attribute__((ext_vector_type(8)));
typedef unsigned int v2u __attribute__((ext_vector_type(2)));

__device__ __forceinline__ v2f pk_fma(v2f a, v2f b, v2f c) {
    return __builtin_elementwise_fma(a, b, c);   // -> v_pk_fma_f32
}

// packed fast reciprocal: bit-trick estimate + 1 Newton. Valid x in [1, ~1e38].
// max rel err ~0.1% after Newton — inside this problem's error budget (R5: 0.031 abs).
__device__ __forceinline__ v2f pk_rcp1(v2f x) {
    v2u xb; __builtin_memcpy(&xb, &x, 8);
    v2u yb = (v2u){0x7EF311C3u, 0x7EF311C3u} - xb;
    v2f y;  __builtin_memcpy(&y, &yb, 8);
    v2f u = pk_fma(-x, y, (v2f){2.0f, 2.0f});    // 2 - x*y
    return y * u;
}

__device__ __forceinline__ float fexp2(float x) {
#if __has_builtin(__builtin_amdgcn_exp2f)
    return __builtin_amdgcn_exp2f(x);
#else
    float r; asm("v_exp_f32 %0, %1" : "=v"(r) : "v"(x)); return r;
#endif
}
__device__ __forceinline__ float frcp(float x) {
#if __has_builtin(__builtin_amdgcn_rcpf)
    return __builtin_amdgcn_rcpf(x);
#else
    float r; asm("v_rcp_f32 %0, %1" : "=v"(r) : "v"(x)); return r;
#endif
}
__device__ __forceinline__ float frsq(float x) {
#if __has_builtin(__builtin_amdgcn_rsqf)
    return __builtin_amdgcn_rsqf(x);
#else
    float r; asm("v_rsq_f32 %0, %1" : "=v"(r) : "v"(x)); return r;
#endif
}

// ---------------------------------------------------------------------------
// Transform kernel. Record per (i,j), 16 floats, (g,j) interleaved:
//  [0,1]=(S*gw0,S*jw0) [2,3]=(S*gw1,S*jw1) [4,5]=(S*gw2,S*jw2)
//  [6,7]=(S*gw3,S*jw3) [8,9]=(S*gb1,S*jb1) [10,11]=(-2g20,-2g21)
//  [12,13]=(-2g22,-2jW2) [14,15]=(e^{2jw0}, e^{-2jw0})
// ---------------------------------------------------------------------------
__global__ __launch_bounds__(HH) void xform_kernel(
    const float* __restrict__ gW1, const float* __restrict__ gb1,
    const float* __restrict__ gW2, const float* __restrict__ gb2,
    const float* __restrict__ jW1, const float* __restrict__ jb1,
    const float* __restrict__ jW2,
    float* __restrict__ recA, float* __restrict__ G)
{
    const int i = blockIdx.x;    // step
    const int j = threadIdx.x;   // hidden unit
    float* r = recA + ((size_t)(i*HH + j)) * 16;

    const float* gw = gW1 + (size_t)(i*HH + j)*4;
    const float* jw = jW1 + (size_t)(i*HH + j)*4;
    float jw0 = jw[0];
    r[0] = SCALE*gw[0]; r[1] = SCALE*jw0;
    r[2] = SCALE*gw[1]; r[3] = SCALE*jw[1];
    r[4] = SCALE*gw[2]; r[5] = SCALE*jw[2];
    r[6] = SCALE*gw[3]; r[7] = SCALE*jw[3];
    r[8] = SCALE*gb1[i*HH + j];
    r[9] = SCALE*jb1[i*HH + j];
    float g20 = gW2[i*3*HH + 0*HH + j];
    float g21 = gW2[i*3*HH + 1*HH + j];
    float g22 = gW2[i*3*HH + 2*HH + j];
    r[10] = -2.0f*g20; r[11] = -2.0f*g21;
    r[12] = -2.0f*g22; r[13] = -2.0f*jW2[i*HH + j];
    r[14] = exp2f( SCALE*jw0);
    r[15] = exp2f(-SCALE*jw0);

    __shared__ float sh[3*HH];
    sh[0*HH + j] = g20; sh[1*HH + j] = g21; sh[2*HH + j] = g22;
    __syncthreads();
    if (j < 3) {
        float s = gb2[i*3 + j];
        for (int t = 0; t < HH; ++t) s += sh[j*HH + t];
        G[i*4 + j] = s;
    }
}

// ---------------------------------------------------------------------------
// Main kernel. Block = 256 threads = 64 batch slots x 4 j-quarters (each
// wave is one quarter -> jq wave-uniform, weight loads scalar). Each thread
// runs 32 hidden units; quarters combine via LDS. 8192 blocks = 32768 waves
// -> deep wave pool per SIMD, short waves, small drain tail.
// ---------------------------------------------------------------------------
__global__ __launch_bounds__(256) void step_kernel(
    const float* __restrict__ N, const float* __restrict__ X,
    const float* __restrict__ T, const float* __restrict__ dB,
    const float* __restrict__ recA, const float* __restrict__ G,
    float* __restrict__ C)
{
    const int tid  = threadIdx.x;
    const int i    = blockIdx.x >> 8;          // step (block-uniform)
    const int bblk = blockIdx.x & 255;
    const int bl   = tid & 63;                 // local batch slot
    const int jq   = __builtin_amdgcn_readfirstlane(tid >> 6);  // j-quarter -> SGPR
    const int b    = bblk*64 + bl;
    const int ib   = i*BB + b;

    const float Ni = N[ib];
    const float x0 = X[(size_t)ib*3 + 0], x1 = X[(size_t)ib*3 + 1], x2 = X[(size_t)ib*3 + 2];

    const v8f* rec8 = (const v8f*)(recA + (size_t)i*HH*16) + (size_t)jq*64;

    const v2f one = {1.0f, 1.0f};
    const v2f c25 = {25.0f, 25.0f};

    v2f ga01 = {0.f, 0.f};   // (sum -2g20*rg, sum -2g21*rg)
    v2f g2a0 = {0.f, 0.f};   // (sum -2g22*rg, sum -2jW2*r0)
    v2f aPM  = {0.f, 0.f};   // (sum -2jW2*rp, sum -2jW2*rm)

#pragma unroll 4
    for (int t = 0; t < 32; ++t) {
        const v8f A  = rec8[2*t + 0];    // W1 rows, interleaved (g,j)
        const v8f Bv = rec8[2*t + 1];    // [gb,jb, -2g20,-2g21, -2g22,-2jW2, cp,cm]

        v2f acc = {Bv[0], Bv[1]};
        acc = pk_fma((v2f){A[0], A[1]}, (v2f){Ni, Ni}, acc);
        acc = pk_fma((v2f){A[2], A[3]}, (v2f){x0, x0}, acc);
        acc = pk_fma((v2f){A[4], A[5]}, (v2f){x1, x1}, acc);
        acc = pk_fma((v2f){A[6], A[7]}, (v2f){x2, x2}, acc);
        acc = __builtin_elementwise_min(acc, c25);   // keep exp2 finite (rcp1 domain)

        const float eg = fexp2(acc[0]);
        const float eb = fexp2(acc[1]);

        v2f t01 = (v2f){eg, eb} + one;                              // (tg, t0)
        v2f tpm = pk_fma((v2f){eb, eb}, (v2f){Bv[6], Bv[7]}, one);  // (tp, tm)

        v2f r01 = pk_rcp1(t01);   // (1/tg, 1/t0)
        v2f rpm = pk_rcp1(tpm);   // (1/tp, 1/tm)

        ga01 = pk_fma((v2f){Bv[2], Bv[3]}, (v2f){r01[0], r01[0]}, ga01);
        g2a0 = pk_fma((v2f){Bv[4], Bv[5]}, r01, g2a0);
        aPM  = pk_fma((v2f){Bv[5], Bv[5]}, rpm, aPM);
    }

    // combine 4 quarter-partials: quarters 1..3 write, quarter 0 reduces
    __shared__ float sh[3][6][64];
    if (jq) {
        float* s = &sh[jq-1][0][bl];
        s[0*64] = ga01[0]; s[1*64] = ga01[1]; s[2*64] = g2a0[0];
        s[3*64] = g2a0[1]; s[4*64] = aPM[0];  s[5*64] = aPM[1];
    }
    __syncthreads();
    if (!jq) {
        float v0 = ga01[0], v1 = ga01[1], v2 = g2a0[0];
        float v3 = g2a0[1], v4 = aPM[0],  v5 = aPM[1];
#pragma unroll
        for (int q = 0; q < 3; ++q) {
            v0 += sh[q][0][bl]; v1 += sh[q][1][bl]; v2 += sh[q][2][bl];
            v3 += sh[q][3][bl]; v4 += sh[q][4][bl]; v5 += sh[q][5][bl];
        }
        const float g0 = G[i*4 + 0] + v0;
        const float g1 = G[i*4 + 1] + v1;
        const float g2 = G[i*4 + 2] + v2;
        const float a0 = v3;
        const float aP = v4;
        const float aM = v5;

        const float Np1 = N[ib + BB];
        const float d0 = dB[(size_t)ib*3 + 0], d1 = dB[(size_t)ib*3 + 1], d2 = dB[(size_t)ib*3 + 2];
        const float ti = T[i];

        const float gdx = g0*x0 + g1*x1 + g2*x2;          // grad_u . x
        const float ss  = x0*x0 + x1*x1 + x2*x2;          // x . x
        const float gdB = g0*d0 + g1*d1 + g2*d2;          // grad_u . dB
        const float xdB = x0*d0 + x1*d1 + x2*d2;          // x . dB

        const float k = 1.41421356237309505f * frsq(fmaf(0.1f*Ni, Ni, 1.0f));
        // kg^T (I+o)(I-o) dB = k*(g.dB - (x.x)*(g.x)*(x.dB))
        const float grad_bmm = k * (gdB - ss*gdx*xdB);

        const float dp = aP - a0;
        const float dm = aM - a0;

        // alpha = 0.3*sig(0.1 N), beta = 0.2*(1-sig(0.1 N))
        const float sig = frcp(1.0f + fexp2(-0.1f*LOG2E*Ni));
        const float alpha = 0.3f*sig;
        const float beta  = 0.2f - 0.2f*sig;

        const float dd = Np1 - Ni;                        // exact -1/0/+1
        const float jump = (dd > 0.5f) ? dp : ((dd < -0.5f) ? dm : 0.0f);

        const float c = grad_bmm - (alpha*dp + beta*dm)*DTF
                      - 0.05f*DTF*gdx - 0.01f*DTF*ti + jump;
        C[ib] = c;
    }
}

// ---------------------------------------------------------------------------
// Final kernel: u0 via r-MLP parallelized 16 lanes per batch element
// (shuffle-reduce), then 32-step affine scan on the group leader.
// ---------------------------------------------------------------------------
__global__ __launch_bounds__(256) void final_kernel(
    const float* __restrict__ N, const float* __restrict__ X,
    const float* __restrict__ rW1, const float* __restrict__ rb1,
    const float* __restrict__ rW2, const float* __restrict__ rb2,
    const float* __restrict__ C, float* __restrict__ out)
{
    const int gid = blockIdx.x*256 + threadIdx.x;
    const int b = gid >> 4;          // batch element
    const int p = gid & 15;          // 16-way split over hidden units

    const float n0 = N[b];
    const float x0 = X[(size_t)b*3 + 0], x1 = X[(size_t)b*3 + 1], x2 = X[(size_t)b*3 + 2];

    float accw = 0.f, accr = 0.f;
#pragma unroll
    for (int t = 0; t < 8; ++t) {
        const int j = p*8 + t;
        float pre = fmaf(rW1[j*4+0], n0, fmaf(rW1[j*4+1], x0,
                    fmaf(rW1[j*4+2], x1, fmaf(rW1[j*4+3], x2, rb1[j]))));
        float r  = frcp(1.0f + fexp2(SCALE*pre));
        float w2 = rW2[j];
        accw += w2;
        accr = fmaf(w2, r, accr);
    }
    accw += __shfl_down(accw, 8, 16);  accr += __shfl_down(accr, 8, 16);
    accw += __shfl_down(accw, 4, 16);  accr += __shfl_down(accr, 4, 16);
    accw += __shfl_down(accw, 2, 16);  accr += __shfl_down(accr, 2, 16);
    accw += __shfl_down(accw, 1, 16);  accr += __shfl_down(accr, 1, 16);

    if (p == 0) {
        float u = rb2[0] + accw - 2.0f*accr;    // rb2 + sum w2*tanh

        const float sfac = 1.0f + 0.05f*DTF;
#pragma unroll
        for (int i = 0; i < NSTEPS; ++i)
            u = fmaf(u, sfac, C[(size_t)i*BB + b]);
        out[b] = u;

        const int ib = NSTEPS*BB + b;
        out[BB + b] = fmaf(0.1f, N[ib], __cosf(X[(size_t)ib*3]));
    }
}

// ---------------------------------------------------------------------------
extern "C" void kernel_launch(void* const* d_in, const int* in_sizes, int n_in,
                              void* d_out, int out_size, void* d_ws, size_t ws_size,
                              hipStream_t stream)
{
    const float* N   = (const float*)d_in[0];
    const float* X   = (const float*)d_in[1];
    const float* T   = (const float*)d_in[2];
    const float* dB  = (const float*)d_in[3];
    const float* rW1 = (const float*)d_in[4];
    const float* rb1 = (const float*)d_in[5];
    const float* rW2 = (const float*)d_in[6];
    const float* rb2 = (const float*)d_in[7];
    const float* gW1 = (const float*)d_in[8];
    const float* gb1 = (const float*)d_in[9];
    const float* gW2 = (const float*)d_in[10];
    const float* gb2 = (const float*)d_in[11];
    const float* jW1 = (const float*)d_in[12];
    const float* jb1 = (const float*)d_in[13];
    const float* jW2 = (const float*)d_in[14];
    // jb2 (d_in[15]) cancels in dp/dm — unused.

    float* ws   = (float*)d_ws;
    float* C    = ws;                                  // 32*16384 floats
    float* recA = ws + (size_t)NSTEPS*BB;              // 32*128*16 floats
    float* G    = recA + (size_t)NSTEPS*HH*16;         // 128 floats
    float* out  = (float*)d_out;

    xform_kernel<<<NSTEPS, HH, 0, stream>>>(gW1, gb1, gW2, gb2, jW1, jb1, jW2, recA, G);
    step_kernel<<<NSTEPS*(BB/64), 256, 0, stream>>>(N, X, T, dB, recA, G, C);
    final_kernel<<<BB*16/256, 256, 0, stream>>>(N, X, rW1, rb1, rW2, rb2, C, out);
}

// Round 8
// 63.749 us; speedup vs baseline: 1.1172x; 1.0192x over previous
//
#include <hip/hip_runtime.h>
#include <math.h>

#define BB 16384
#define NSTEPS 32
#define HH 128
#define DTF (1.0f/32.0f)
#define SCALE 2.88539008177792681f   // 2*log2(e):  e^{2x} = 2^{SCALE*x}
#define LOG2E 1.44269504088896340f

typedef float v2f __attribute__((ext_vector_type(2)));
typedef float v16f __attribute__((ext_vector_type(16)));
typedef unsigned int v2u __attribute__((ext_vector_type(2)));

// compile-time slice: element-pair k of a v16f (even-aligned -> SGPR pair)
#define SL(v,k) (__builtin_shufflevector((v),(v),2*(k),2*(k)+1))

__device__ __forceinline__ v2f pk_fma(v2f a, v2f b, v2f c) {
    return __builtin_elementwise_fma(a, b, c);   // -> v_pk_fma_f32
}

// packed fast reciprocal: bit-trick estimate + 1 Newton. Valid x in [1, ~1e38].
__device__ __forceinline__ v2f pk_rcp1(v2f x) {
    v2u xb; __builtin_memcpy(&xb, &x, 8);
    v2u yb = (v2u){0x7EF311C3u, 0x7EF311C3u} - xb;
    v2f y;  __builtin_memcpy(&y, &yb, 8);
    v2f u = pk_fma(-x, y, (v2f){2.0f, 2.0f});    // 2 - x*y
    return y * u;
}

__device__ __forceinline__ float fexp2(float x) {
#if __has_builtin(__builtin_amdgcn_exp2f)
    return __builtin_amdgcn_exp2f(x);
#else
    float r; asm("v_exp_f32 %0, %1" : "=v"(r) : "v"(x)); return r;
#endif
}
__device__ __forceinline__ float frcp(float x) {
#if __has_builtin(__builtin_amdgcn_rcpf)
    return __builtin_amdgcn_rcpf(x);
#else
    float r; asm("v_rcp_f32 %0, %1" : "=v"(r) : "v"(x)); return r;
#endif
}
__device__ __forceinline__ float frsq(float x) {
#if __has_builtin(__builtin_amdgcn_rsqf)
    return __builtin_amdgcn_rsqf(x);
#else
    float r; asm("v_rsq_f32 %0, %1" : "=v"(r) : "v"(x)); return r;
#endif
}

// ---------------------------------------------------------------------------
// Transform kernel. NEW layout: per unit-PAIR (j,j+1) at step i, 32 floats:
//  g-record [0..15]:  w0p w1p w2p w3p gbp g20p g21p g22p   (pairs, scaled)
//  j-record [16..31]: jw0p jw1p jw2p jw3p jbp jW2p cpp cmp
// so every packed operand in the hot loop is an even-aligned SGPR pair.
// ---------------------------------------------------------------------------
__global__ __launch_bounds__(HH) void xform_kernel(
    const float* __restrict__ gW1, const float* __restrict__ gb1,
    const float* __restrict__ gW2, const float* __restrict__ gb2,
    const float* __restrict__ jW1, const float* __restrict__ jb1,
    const float* __restrict__ jW2,
    float* __restrict__ recA, float* __restrict__ G)
{
    const int i = blockIdx.x;    // step
    const int j = threadIdx.x;   // hidden unit
    const int pair = j >> 1;
    const int ln   = j & 1;
    float* r = recA + ((size_t)i*64 + pair)*32;

    const float* gw = gW1 + (size_t)(i*HH + j)*4;
    const float* jw = jW1 + (size_t)(i*HH + j)*4;
    float jw0 = jw[0];
    float g20 = gW2[i*3*HH + 0*HH + j];
    float g21 = gW2[i*3*HH + 1*HH + j];
    float g22 = gW2[i*3*HH + 2*HH + j];

    r[ 0+ln] = SCALE*gw[0];
    r[ 2+ln] = SCALE*gw[1];
    r[ 4+ln] = SCALE*gw[2];
    r[ 6+ln] = SCALE*gw[3];
    r[ 8+ln] = SCALE*gb1[i*HH + j];
    r[10+ln] = -2.0f*g20;
    r[12+ln] = -2.0f*g21;
    r[14+ln] = -2.0f*g22;

    r[16+ln] = SCALE*jw0;
    r[18+ln] = SCALE*jw[1];
    r[20+ln] = SCALE*jw[2];
    r[22+ln] = SCALE*jw[3];
    r[24+ln] = SCALE*jb1[i*HH + j];
    r[26+ln] = -2.0f*jW2[i*HH + j];
    r[28+ln] = exp2f( SCALE*jw0);
    r[30+ln] = exp2f(-SCALE*jw0);

    __shared__ float sh[3*HH];
    sh[0*HH + j] = g20; sh[1*HH + j] = g21; sh[2*HH + j] = g22;
    __syncthreads();
    if (j < 3) {
        float s = gb2[i*3 + j];
        for (int t = 0; t < HH; ++t) s += sh[j*HH + t];
        G[i*4 + j] = s;
    }
}

// ---------------------------------------------------------------------------
// Main kernel. Block = 256 = 64 batch slots x 4 j-quarters (jq wave-uniform
// via readfirstlane -> scalar weight loads). Each thread: 16 unit-PAIR
// iterations. SIMD lanes of every packed op = adjacent hidden units, so
// weights fold as SGPR pairs and batch scalars are loop-invariant VGPR
// pairs -> no per-iteration marshalling movs.
// ---------------------------------------------------------------------------
__global__ __launch_bounds__(256) void step_kernel(
    const float* __restrict__ N, const float* __restrict__ X,
    const float* __restrict__ T, const float* __restrict__ dB,
    const float* __restrict__ recA, const float* __restrict__ G,
    float* __restrict__ C)
{
    const int tid  = threadIdx.x;
    const int i    = blockIdx.x >> 8;          // step (block-uniform)
    const int bblk = blockIdx.x & 255;
    const int bl   = tid & 63;                 // local batch slot
    const int jq   = __builtin_amdgcn_readfirstlane(tid >> 6);  // j-quarter -> SGPR
    const int b    = bblk*64 + bl;
    const int ib   = i*BB + b;

    const float Ni = N[ib];
    const float x0 = X[(size_t)ib*3 + 0], x1 = X[(size_t)ib*3 + 1], x2 = X[(size_t)ib*3 + 2];

    // quarter q covers unit-pairs [q*16, q*16+16): 16 x 32 floats = 32 v16f
    const v16f* rec16 = (const v16f*)(recA + (size_t)i*HH*16 + (size_t)jq*512);

    // loop-invariant packed operands (VGPR pairs)
    const v2f Niv  = {Ni, Ni};
    const v2f x0v  = {x0, x0};
    const v2f x1v  = {x1, x1};
    const v2f x2v  = {x2, x2};
    const v2f onev = {1.0f, 1.0f};
    const v2f c25v = {25.0f, 25.0f};

    v2f ga0 = {0.f,0.f}, ga1 = {0.f,0.f}, ga2 = {0.f,0.f};
    v2f a0  = {0.f,0.f}, aP  = {0.f,0.f}, aM  = {0.f,0.f};

#pragma unroll 2
    for (int t = 0; t < 16; ++t) {
        const v16f Rg = rec16[2*t + 0];   // g-record
        const v16f Rj = rec16[2*t + 1];   // j-record

        // ---- g-MLP, units (2t, 2t+1) packed ----
        v2f ag = SL(Rg,4) * onev;                 // bias
        ag = pk_fma(SL(Rg,0), Niv, ag);
        ag = pk_fma(SL(Rg,1), x0v, ag);
        ag = pk_fma(SL(Rg,2), x1v, ag);
        ag = pk_fma(SL(Rg,3), x2v, ag);
        ag = __builtin_elementwise_min(ag, c25v); // keep exp2 finite (rcp1 domain)
        v2f eg; eg.x = fexp2(ag.x); eg.y = fexp2(ag.y);
        v2f rg = pk_rcp1(eg + 1.0f);
        ga0 = pk_fma(SL(Rg,5), rg, ga0);
        ga1 = pk_fma(SL(Rg,6), rg, ga1);
        ga2 = pk_fma(SL(Rg,7), rg, ga2);

        // ---- j-MLP, units (2t, 2t+1) packed, 3 N-shifts share one exp ----
        v2f aj = SL(Rj,4) * onev;
        aj = pk_fma(SL(Rj,0), Niv, aj);
        aj = pk_fma(SL(Rj,1), x0v, aj);
        aj = pk_fma(SL(Rj,2), x1v, aj);
        aj = pk_fma(SL(Rj,3), x2v, aj);
        aj = __builtin_elementwise_min(aj, c25v);
        v2f ej; ej.x = fexp2(aj.x); ej.y = fexp2(aj.y);
        v2f r0 = pk_rcp1(ej + 1.0f);
        v2f rp = pk_rcp1(pk_fma(SL(Rj,6), ej, onev));
        v2f rm = pk_rcp1(pk_fma(SL(Rj,7), ej, onev));
        const v2f w2p = SL(Rj,5);
        a0 = pk_fma(w2p, r0, a0);
        aP = pk_fma(w2p, rp, aP);
        aM = pk_fma(w2p, rm, aM);
    }

    // horizontal: even+odd unit lanes
    const float hga0 = ga0.x + ga0.y;
    const float hga1 = ga1.x + ga1.y;
    const float hga2 = ga2.x + ga2.y;
    const float ha0  = a0.x  + a0.y;
    const float haP  = aP.x  + aP.y;
    const float haM  = aM.x  + aM.y;

    // combine 4 quarter-partials: quarters 1..3 write, quarter 0 reduces
    __shared__ float sh[3][6][64];
    if (jq) {
        float* s = &sh[jq-1][0][bl];
        s[0*64] = hga0; s[1*64] = hga1; s[2*64] = hga2;
        s[3*64] = ha0;  s[4*64] = haP;  s[5*64] = haM;
    }
    __syncthreads();
    if (!jq) {
        float v0 = hga0, v1 = hga1, v2 = hga2;
        float v3 = ha0,  v4 = haP,  v5 = haM;
#pragma unroll
        for (int q = 0; q < 3; ++q) {
            v0 += sh[q][0][bl]; v1 += sh[q][1][bl]; v2 += sh[q][2][bl];
            v3 += sh[q][3][bl]; v4 += sh[q][4][bl]; v5 += sh[q][5][bl];
        }
        const float g0 = G[i*4 + 0] + v0;
        const float g1 = G[i*4 + 1] + v1;
        const float g2 = G[i*4 + 2] + v2;
        const float A0 = v3;
        const float AP = v4;
        const float AM = v5;

        const float Np1 = N[ib + BB];
        const float d0 = dB[(size_t)ib*3 + 0], d1 = dB[(size_t)ib*3 + 1], d2 = dB[(size_t)ib*3 + 2];
        const float ti = T[i];

        const float gdx = g0*x0 + g1*x1 + g2*x2;          // grad_u . x
        const float ss  = x0*x0 + x1*x1 + x2*x2;          // x . x
        const float gdB = g0*d0 + g1*d1 + g2*d2;          // grad_u . dB
        const float xdB = x0*d0 + x1*d1 + x2*d2;          // x . dB

        const float k = 1.41421356237309505f * frsq(fmaf(0.1f*Ni, Ni, 1.0f));
        // kg^T (I+o)(I-o) dB = k*(g.dB - (x.x)*(g.x)*(x.dB))
        const float grad_bmm = k * (gdB - ss*gdx*xdB);

        const float dp = AP - A0;
        const float dm = AM - A0;

        // alpha = 0.3*sig(0.1 N), beta = 0.2*(1-sig(0.1 N))
        const float sig = frcp(1.0f + fexp2(-0.1f*LOG2E*Ni));
        const float alpha = 0.3f*sig;
        const float beta  = 0.2f - 0.2f*sig;

        const float dd = Np1 - Ni;                        // exact -1/0/+1
        const float jump = (dd > 0.5f) ? dp : ((dd < -0.5f) ? dm : 0.0f);

        const float c = grad_bmm - (alpha*dp + beta*dm)*DTF
                      - 0.05f*DTF*gdx - 0.01f*DTF*ti + jump;
        C[ib] = c;
    }
}

// ---------------------------------------------------------------------------
// Final kernel: u0 via r-MLP parallelized 16 lanes per batch element
// (shuffle-reduce), then 32-step affine scan on the group leader.
// ---------------------------------------------------------------------------
__global__ __launch_bounds__(256) void final_kernel(
    const float* __restrict__ N, const float* __restrict__ X,
    const float* __restrict__ rW1, const float* __restrict__ rb1,
    const float* __restrict__ rW2, const float* __restrict__ rb2,
    const float* __restrict__ C, float* __restrict__ out)
{
    const int gid = blockIdx.x*256 + threadIdx.x;
    const int b = gid >> 4;          // batch element
    const int p = gid & 15;          // 16-way split over hidden units

    const float n0 = N[b];
    const float x0 = X[(size_t)b*3 + 0], x1 = X[(size_t)b*3 + 1], x2 = X[(size_t)b*3 + 2];

    float accw = 0.f, accr = 0.f;
#pragma unroll
    for (int t = 0; t < 8; ++t) {
        const int j = p*8 + t;
        float pre = fmaf(rW1[j*4+0], n0, fmaf(rW1[j*4+1], x0,
                    fmaf(rW1[j*4+2], x1, fmaf(rW1[j*4+3], x2, rb1[j]))));
        float r  = frcp(1.0f + fexp2(SCALE*pre));
        float w2 = rW2[j];
        accw += w2;
        accr = fmaf(w2, r, accr);
    }
    accw += __shfl_down(accw, 8, 16);  accr += __shfl_down(accr, 8, 16);
    accw += __shfl_down(accw, 4, 16);  accr += __shfl_down(accr, 4, 16);
    accw += __shfl_down(accw, 2, 16);  accr += __shfl_down(accr, 2, 16);
    accw += __shfl_down(accw, 1, 16);  accr += __shfl_down(accr, 1, 16);

    if (p == 0) {
        float u = rb2[0] + accw - 2.0f*accr;    // rb2 + sum w2*tanh

        const float sfac = 1.0f + 0.05f*DTF;
#pragma unroll
        for (int i = 0; i < NSTEPS; ++i)
            u = fmaf(u, sfac, C[(size_t)i*BB + b]);
        out[b] = u;

        const int ib = NSTEPS*BB + b;
        out[BB + b] = fmaf(0.1f, N[ib], __cosf(X[(size_t)ib*3]));
    }
}

// ---------------------------------------------------------------------------
extern "C" void kernel_launch(void* const* d_in, const int* in_sizes, int n_in,
                              void* d_out, int out_size, void* d_ws, size_t ws_size,
                              hipStream_t stream)
{
    const float* N   = (const float*)d_in[0];
    const float* X   = (const float*)d_in[1];
    const float* T   = (const float*)d_in[2];
    const float* dB  = (const float*)d_in[3];
    const float* rW1 = (const float*)d_in[4];
    const float* rb1 = (const float*)d_in[5];
    const float* rW2 = (const float*)d_in[6];
    const float* rb2 = (const float*)d_in[7];
    const float* gW1 = (const float*)d_in[8];
    const float* gb1 = (const float*)d_in[9];
    const float* gW2 = (const float*)d_in[10];
    const float* gb2 = (const float*)d_in[11];
    const float* jW1 = (const float*)d_in[12];
    const float* jb1 = (const float*)d_in[13];
    const float* jW2 = (const float*)d_in[14];
    // jb2 (d_in[15]) cancels in dp/dm — unused.

    float* ws   = (float*)d_ws;
    float* C    = ws;                                  // 32*16384 floats
    float* recA = ws + (size_t)NSTEPS*BB;              // 32*128*16 floats
    float* G    = recA + (size_t)NSTEPS*HH*16;         // 128 floats
    float* out  = (float*)d_out;

    xform_kernel<<<NSTEPS, HH, 0, stream>>>(gW1, gb1, gW2, gb2, jW1, jb1, jW2, recA, G);
    step_kernel<<<NSTEPS*(BB/64), 256, 0, stream>>>(N, X, T, dB, recA, G, C);
    final_kernel<<<BB*16/256, 256, 0, stream>>>(N, X, rW1, rb1, rW2, rb2, C, out);
}